// Round 2
// baseline (502.795 us; speedup 1.0000x reference)
//
#include <hip/hip_runtime.h>
#include <hip/hip_bf16.h>
#include <hip/hip_fp16.h>
#include <stdint.h>

#define B_ 2
#define F_ 2
#define C_ 128
#define D_ 96
#define H_ 48
#define W_ 128
#define HW_ (H_*W_)
#define EPS_ 1e-7f
#define DCHUNK 4

typedef _Float16 f16x2 __attribute__((ext_vector_type(2)));
union U32H2 { unsigned u; f16x2 h; };

__device__ __forceinline__ f16x2 habs2(f16x2 x){
    U32H2 t; t.h = x; t.u &= 0x7fff7fffu; return t.h;
}
__device__ __forceinline__ f16x2 asH2(unsigned u){
    U32H2 t; t.u = u; return t.h;
}
__device__ __forceinline__ f16x2 h2bc(float v){
    _Float16 h = (_Float16)v; f16x2 r; r[0] = h; r[1] = h; return r;
}

#if __has_builtin(__builtin_amdgcn_fdot2)
#define HAS_FDOT2 1
#endif

__device__ __forceinline__ float accum2(f16x2 d, float acc){
#ifdef HAS_FDOT2
    const f16x2 one = {(_Float16)1.0f, (_Float16)1.0f};
    return __builtin_amdgcn_fdot2(d, one, acc, false);
#else
    return acc + (float)d[0] + (float)d[1];
#endif
}

__device__ __forceinline__ float depth_bin(int d){
    return (float)(0.1 + (double)d * (19.9 / 95.0));
}

// transpose + f32->f16: src [nslice][C][HW] f32 -> dst [nslice][HW][C] f16
__global__ void transpose_kernel(const float* __restrict__ src,
                                 _Float16* __restrict__ dst){
    __shared__ float tile[32][33];
    const int tx = threadIdx.x & 31, ty = threadIdx.x >> 5;   // ty 0..7
    const int nc = C_ / 32;     // 4
    const int np = HW_ / 32;    // 192
    int bid = blockIdx.x;
    int p0 = (bid % np) * 32;
    int c0 = ((bid / np) % nc) * 32;
    int s  = bid / (np * nc);
    const float* sp = src + (size_t)s * C_ * HW_;
    _Float16* dp = dst + (size_t)s * HW_ * C_;
#pragma unroll
    for (int j = 0; j < 4; ++j){
        int c = c0 + ty + j * 8;
        tile[ty + j * 8][tx] = sp[(size_t)c * HW_ + p0 + tx];
    }
    __syncthreads();
#pragma unroll
    for (int j = 0; j < 4; ++j){
        int p = p0 + ty + j * 8;
        dp[(size_t)p * C_ + c0 + tx] = (_Float16)tile[tx][ty + j * 8];
    }
}

template<bool TR>
__global__ __launch_bounds__(128)
void cost_kernel(const float* __restrict__ cur_f32,
                 const float* __restrict__ look_f32,
                 const float* __restrict__ poses,
                 const float* __restrict__ Kmat,
                 const float* __restrict__ invKm,
                 const _Float16* __restrict__ LT,
                 const _Float16* __restrict__ CT,
                 float* __restrict__ out_cost)
{
    const int nd = D_ / DCHUNK;                 // 24
    int bid = blockIdx.x;
    int dci = bid % nd;
    int h   = (bid / nd) % H_;
    int b   = bid / (nd * H_);
    int w = threadIdx.x;
    int d0 = dci * DCHUNK;

    float u = (float)w, v = (float)h;
    const float* iK = invKm + b * 16;
    float dirx = iK[0]*u + iK[1]*v + iK[2];
    float diry = iK[4]*u + iK[5]*v + iK[6];
    float dirz = iK[8]*u + iK[9]*v + iK[10];
    const float* Kb = Kmat + b * 16;

    const bool border = (h >= 2 && h <= H_-3 && w >= 2 && w <= W_-3);

    float diffs[F_][DCHUNK];

#pragma unroll
    for (int f = 0; f < F_; ++f){
        const float* ps = poses + ((size_t)b * F_ + f) * 16;
        float psum = 0.f;
#pragma unroll
        for (int i = 0; i < 16; ++i) psum += ps[i];
        const float validf = (psum != 0.0f) ? 1.0f : 0.0f;

        float P[3][4];
#pragma unroll
        for (int i = 0; i < 3; ++i)
#pragma unroll
            for (int j = 0; j < 4; ++j)
                P[i][j] = Kb[i*4+0]*ps[0*4+j] + Kb[i*4+1]*ps[1*4+j]
                        + Kb[i*4+2]*ps[2*4+j] + Kb[i*4+3]*ps[3*4+j];

        float qx = P[0][0]*dirx + P[0][1]*diry + P[0][2]*dirz;
        float qy = P[1][0]*dirx + P[1][1]*diry + P[1][2]*dirz;
        float qz = P[2][0]*dirx + P[2][1]*diry + P[2][2]*dirz;

        int   o00[DCHUNK], o01[DCHUNK], o10[DCHUNK], o11[DCHUNK];
        f16x2 w00p[DCHUNK], w01p[DCHUNK], w10p[DCHUNK], w11p[DCHUNK];
        float fw00[DCHUNK], fw01[DCHUNK], fw10[DCHUNK], fw11[DCHUNK];
        float edgev[DCHUNK];
        bool anyEdge = false;

#pragma unroll
        for (int j = 0; j < DCHUNK; ++j){
            float dv = depth_bin(d0 + j);
            float cz = qz*dv + P[2][3] + EPS_;
            float inv = 1.0f / cz;
            float x = (qx*dv + P[0][3]) * inv;
            float y = (qy*dv + P[1][3]) * inv;
            float x0f = floorf(x), y0f = floorf(y);
            float x1f = x0f + 1.0f, y1f = y0f + 1.0f;
            float wx1 = x - x0f, wx0 = 1.0f - wx1;
            float wy1 = y - y0f, wy0 = 1.0f - wy1;
            bool vx0 = (x0f >= 0.f) && (x0f <= (float)(W_-1));
            bool vx1 = (x1f >= 0.f) && (x1f <= (float)(W_-1));
            bool vy0 = (y0f >= 0.f) && (y0f <= (float)(H_-1));
            bool vy1 = (y1f >= 0.f) && (y1f <= (float)(H_-1));
            int ix0 = (int)fminf(fmaxf(x0f, 0.f), (float)(W_-1));
            int ix1 = (int)fminf(fmaxf(x1f, 0.f), (float)(W_-1));
            int iy0 = (int)fminf(fmaxf(y0f, 0.f), (float)(H_-1));
            int iy1 = (int)fminf(fmaxf(y1f, 0.f), (float)(H_-1));
            float w00 = (vy0 && vx0) ? wy0*wx0 : 0.f;
            float w01 = (vy0 && vx1) ? wy0*wx1 : 0.f;
            float w10 = (vy1 && vx0) ? wy1*wx0 : 0.f;
            float w11 = (vy1 && vx1) ? wy1*wx1 : 0.f;
            fw00[j]=w00; fw01[j]=w01; fw10[j]=w10; fw11[j]=w11;
            w00p[j] = h2bc(w00); w01p[j] = h2bc(w01);
            w10p[j] = h2bc(w10); w11p[j] = h2bc(w11);
            edgev[j] = (border && x >= 2.f && x <= (float)(W_-2)
                               && y >= 2.f && y <= (float)(H_-2)) ? 1.0f : 0.0f;
            anyEdge |= (edgev[j] != 0.0f);
            if (TR){
                o00[j] = (iy0*W_ + ix0) * (C_*2);
                o01[j] = (iy0*W_ + ix1) * (C_*2);
                o10[j] = (iy1*W_ + ix0) * (C_*2);
                o11[j] = (iy1*W_ + ix1) * (C_*2);
            } else {
                o00[j] = iy0*W_ + ix0;
                o01[j] = iy0*W_ + ix1;
                o10[j] = iy1*W_ + ix0;
                o11[j] = iy1*W_ + ix1;
            }
        }

        float acc[DCHUNK] = {0.f, 0.f, 0.f, 0.f};
        // wave-level skip: if no lane in this wave has any edge!=0, the
        // outputs of this f are all zero -> skip the channel loop entirely.
        bool waveWork = (__ballot(anyEdge ? 1 : 0) != 0ull) && (validf != 0.0f);

        if (TR){
            if (waveWork){
                const char* lb = (const char*)LT + ((size_t)(b*F_ + f) * HW_ * C_) * 2;
                const char* cb = (const char*)CT + (((size_t)b * HW_ + h*W_ + w) * C_) * 2;
#pragma unroll 2
                for (int c8 = 0; c8 < C_/8; ++c8){
                    uint4 cu = *(const uint4*)(cb + c8*16);
#pragma unroll
                    for (int j = 0; j < DCHUNK; ++j){
                        uint4 ta = *(const uint4*)(lb + o00[j] + c8*16);
                        uint4 tb = *(const uint4*)(lb + o01[j] + c8*16);
                        uint4 tc = *(const uint4*)(lb + o10[j] + c8*16);
                        uint4 td = *(const uint4*)(lb + o11[j] + c8*16);
                        f16x2 s0 = asH2(ta.x)*w00p[j] + asH2(tb.x)*w01p[j]
                                 + asH2(tc.x)*w10p[j] + asH2(td.x)*w11p[j];
                        acc[j] = accum2(habs2(s0 - asH2(cu.x)), acc[j]);
                        f16x2 s1 = asH2(ta.y)*w00p[j] + asH2(tb.y)*w01p[j]
                                 + asH2(tc.y)*w10p[j] + asH2(td.y)*w11p[j];
                        acc[j] = accum2(habs2(s1 - asH2(cu.y)), acc[j]);
                        f16x2 s2 = asH2(ta.z)*w00p[j] + asH2(tb.z)*w01p[j]
                                 + asH2(tc.z)*w10p[j] + asH2(td.z)*w11p[j];
                        acc[j] = accum2(habs2(s2 - asH2(cu.z)), acc[j]);
                        f16x2 s3 = asH2(ta.w)*w00p[j] + asH2(tb.w)*w01p[j]
                                 + asH2(tc.w)*w10p[j] + asH2(td.w)*w11p[j];
                        acc[j] = accum2(habs2(s3 - asH2(cu.w)), acc[j]);
                    }
                }
            }
        } else {
            if (waveWork){
                const float* lb = look_f32 + (size_t)(b*F_ + f) * C_ * HW_;
                const float* cb = cur_f32 + (size_t)b * C_ * HW_ + h*W_ + w;
#pragma unroll 2
                for (int c = 0; c < C_; ++c){
                    float cf = cb[(size_t)c * HW_];
                    const float* lc = lb + (size_t)c * HW_;
#pragma unroll
                    for (int j = 0; j < DCHUNK; ++j){
                        float wv = fw00[j]*lc[o00[j]] + fw01[j]*lc[o01[j]]
                                 + fw10[j]*lc[o10[j]] + fw11[j]*lc[o11[j]];
                        acc[j] += fabsf(wv - cf);
                    }
                }
            }
        }

#pragma unroll
        for (int j = 0; j < DCHUNK; ++j)
            diffs[f][j] = acc[j] * (1.0f / C_) * edgev[j] * validf;
    }

    size_t ob = ((size_t)b * D_ + d0) * HW_ + h*W_ + w;
#pragma unroll
    for (int j = 0; j < DCHUNK; ++j){
        float df0 = diffs[0][j], df1 = diffs[1][j];
        float cnt = (df0 > 0.f ? 1.f : 0.f) + (df1 > 0.f ? 1.f : 0.f);
        out_cost[ob + (size_t)j * HW_] = (df0 + df1) / (cnt + EPS_);
    }
}

__global__ void finalize_kernel(float* __restrict__ cost, float* __restrict__ missing){
    int t = blockIdx.x * blockDim.x + threadIdx.x;
    if (t >= B_ * HW_) return;
    int b = t / HW_;
    int p = t % HW_;
    float* cp = cost + (size_t)b * D_ * HW_ + p;
    float mx = 0.f;  // cost values are >= 0
    for (int d = 0; d < D_; ++d) mx = fmaxf(mx, cp[(size_t)d * HW_]);
    for (int d = 0; d < D_; ++d){
        float vv = cp[(size_t)d * HW_];
        float miss = (vv == 0.0f) ? 1.0f : 0.0f;
        cp[(size_t)d * HW_] = (vv == 0.0f) ? mx : vv;
        missing[(size_t)b * D_ * HW_ + (size_t)d * HW_ + p] = miss;
    }
}

extern "C" void kernel_launch(void* const* d_in, const int* in_sizes, int n_in,
                              void* d_out, int out_size, void* d_ws, size_t ws_size,
                              hipStream_t stream){
    const float* cur   = (const float*)d_in[0];
    const float* look  = (const float*)d_in[1];
    const float* poses = (const float*)d_in[2];
    const float* Kmat  = (const float*)d_in[3];
    const float* invKm = (const float*)d_in[4];
    float* cost    = (float*)d_out;
    float* missing = cost + (size_t)B_ * D_ * HW_;

    const size_t ltBytes = (size_t)B_ * F_ * HW_ * C_ * 2;
    const size_t ctBytes = (size_t)B_ * HW_ * C_ * 2;
    const bool useTR = (ws_size >= ltBytes + ctBytes);
    const int nblocks = B_ * H_ * (D_/DCHUNK);

    if (useTR){
        _Float16* LT = (_Float16*)d_ws;
        _Float16* CT = (_Float16*)((char*)d_ws + ltBytes);
        transpose_kernel<<<(B_*F_)*(C_/32)*(HW_/32), 256, 0, stream>>>(look, LT);
        transpose_kernel<<<B_*(C_/32)*(HW_/32), 256, 0, stream>>>(cur, CT);
        cost_kernel<true><<<nblocks, 128, 0, stream>>>(cur, look, poses, Kmat, invKm, LT, CT, cost);
    } else {
        cost_kernel<false><<<nblocks, 128, 0, stream>>>(cur, look, poses, Kmat, invKm, nullptr, nullptr, cost);
    }
    finalize_kernel<<<(B_*HW_ + 255)/256, 256, 0, stream>>>(cost, missing);
}

// Round 3
// 289.847 us; speedup vs baseline: 1.7347x; 1.7347x over previous
//
#include <hip/hip_runtime.h>
#include <hip/hip_bf16.h>
#include <hip/hip_fp16.h>
#include <stdint.h>

#define B_ 2
#define F_ 2
#define C_ 128
#define D_ 96
#define H_ 48
#define W_ 128
#define HW_ (H_*W_)
#define EPS_ 1e-7f
#define NITEM (F_*D_)   // 192

typedef _Float16 f16x2 __attribute__((ext_vector_type(2)));
union U32H2 { unsigned u; f16x2 h; };

__device__ __forceinline__ f16x2 habs2(f16x2 x){
    U32H2 t; t.h = x; t.u &= 0x7fff7fffu; return t.h;
}
__device__ __forceinline__ f16x2 asH2(unsigned u){
    U32H2 t; t.u = u; return t.h;
}
__device__ __forceinline__ unsigned dupf16(float w){
    U32H2 t; _Float16 h = (_Float16)w; t.h[0] = h; t.h[1] = h; return t.u;
}
__device__ __forceinline__ f16x2 pk2(float a, float b){
    f16x2 r; r[0] = (_Float16)a; r[1] = (_Float16)b; return r;
}

#if __has_builtin(__builtin_amdgcn_fdot2)
#define HAS_FDOT2 1
#endif

__device__ __forceinline__ float sum2(f16x2 d){
#ifdef HAS_FDOT2
    const f16x2 one = {(_Float16)1.0f, (_Float16)1.0f};
    return __builtin_amdgcn_fdot2(d, one, 0.0f, false);
#else
    return (float)d[0] + (float)d[1];
#endif
}

__device__ __forceinline__ float depth_bin(int d){
    return (float)(0.1 + (double)d * (19.9 / 95.0));
}

// transpose + f32->f16: src [nslice][C][HW] f32 -> dst [nslice][HW][C] f16
__global__ void transpose_kernel(const float* __restrict__ src,
                                 _Float16* __restrict__ dst){
    __shared__ float tile[32][33];
    const int tx = threadIdx.x & 31, ty = threadIdx.x >> 5;
    const int nc = C_ / 32;     // 4
    const int np = HW_ / 32;    // 192
    int bid = blockIdx.x;
    int p0 = (bid % np) * 32;
    int c0 = ((bid / np) % nc) * 32;
    int s  = bid / (np * nc);
    const float* sp = src + (size_t)s * C_ * HW_;
    _Float16* dp = dst + (size_t)s * HW_ * C_;
#pragma unroll
    for (int j = 0; j < 4; ++j){
        int c = c0 + ty + j * 8;
        tile[ty + j * 8][tx] = sp[(size_t)c * HW_ + p0 + tx];
    }
    __syncthreads();
#pragma unroll
    for (int j = 0; j < 4; ++j){
        int p = p0 + ty + j * 8;
        dp[(size_t)p * C_ + c0 + tx] = (_Float16)tile[tx][ty + j * 8];
    }
}

struct __align__(16) Meta {
    uint4 a;      // 4 tap byte offsets (wave-uniform)
    uint4 wd;     // 4 bilinear weights, f16 duplicated into both halves
    float edge;   // edge * validf (wave-uniform); 0 => whole (d,f) skipped
    float pad0, pad1, pad2;
};

// one wave per output pixel; lane l covers channels 2l, 2l+1
template<bool TR>
__global__ __launch_bounds__(256)
void cost_kernel(const float* __restrict__ cur_f32,
                 const float* __restrict__ look_f32,
                 const float* __restrict__ poses,
                 const float* __restrict__ Kmat,
                 const float* __restrict__ invKm,
                 const _Float16* __restrict__ LT,
                 const _Float16* __restrict__ CT,
                 float* __restrict__ out_cost,
                 float* __restrict__ out_missing)
{
    __shared__ Meta meta[4][NITEM];   // per-wave private; no block barriers used

    const int wid  = threadIdx.x >> 6;
    const int lane = threadIdx.x & 63;
    const int pg   = blockIdx.x * 4 + wid;        // 0 .. B*HW-1
    const int b    = pg / HW_;
    const int pix  = pg % HW_;
    const int h    = pix / W_;
    const int w    = pix % W_;

    const size_t ob = (size_t)b * D_ * HW_ + pix;

    // border fast path: whole column is cost=0, missing=1
    if (h < 2 || h > H_-3 || w < 2 || w > W_-3){
        out_cost[ob + (size_t)lane * HW_] = 0.f;
        out_missing[ob + (size_t)lane * HW_] = 1.f;
        if (lane < 32){
            out_cost[ob + (size_t)(64+lane) * HW_] = 0.f;
            out_missing[ob + (size_t)(64+lane) * HW_] = 1.f;
        }
        return;
    }

    // ---- lane-parallel projection precompute: 3 items per lane ----
    {
        const float* iK = invKm + b * 16;
        const float u = (float)w, v = (float)h;
        const float dirx = iK[0]*u + iK[1]*v + iK[2];
        const float diry = iK[4]*u + iK[5]*v + iK[6];
        const float dirz = iK[8]*u + iK[9]*v + iK[10];
        const float* Kb = Kmat + b * 16;

        for (int it = lane; it < NITEM; it += 64){
            int f = it / D_;
            int d = it % D_;
            const float* ps = poses + ((size_t)b * F_ + f) * 16;
            float psum = 0.f;
#pragma unroll
            for (int i = 0; i < 16; ++i) psum += ps[i];
            const float validf = (psum != 0.0f) ? 1.0f : 0.0f;

            float P[3][4];
#pragma unroll
            for (int i = 0; i < 3; ++i)
#pragma unroll
                for (int j = 0; j < 4; ++j)
                    P[i][j] = Kb[i*4+0]*ps[0*4+j] + Kb[i*4+1]*ps[1*4+j]
                            + Kb[i*4+2]*ps[2*4+j] + Kb[i*4+3]*ps[3*4+j];

            float qx = P[0][0]*dirx + P[0][1]*diry + P[0][2]*dirz;
            float qy = P[1][0]*dirx + P[1][1]*diry + P[1][2]*dirz;
            float qz = P[2][0]*dirx + P[2][1]*diry + P[2][2]*dirz;

            float dv = depth_bin(d);
            float cz = qz*dv + P[2][3] + EPS_;
            float x = (qx*dv + P[0][3]) / cz;
            float y = (qy*dv + P[1][3]) / cz;
            float x0f = floorf(x), y0f = floorf(y);
            float x1f = x0f + 1.0f, y1f = y0f + 1.0f;
            float wx1 = x - x0f, wx0 = 1.0f - wx1;
            float wy1 = y - y0f, wy0 = 1.0f - wy1;
            bool vx0 = (x0f >= 0.f) && (x0f <= (float)(W_-1));
            bool vx1 = (x1f >= 0.f) && (x1f <= (float)(W_-1));
            bool vy0 = (y0f >= 0.f) && (y0f <= (float)(H_-1));
            bool vy1 = (y1f >= 0.f) && (y1f <= (float)(H_-1));
            int ix0 = (int)fminf(fmaxf(x0f, 0.f), (float)(W_-1));
            int ix1 = (int)fminf(fmaxf(x1f, 0.f), (float)(W_-1));
            int iy0 = (int)fminf(fmaxf(y0f, 0.f), (float)(H_-1));
            int iy1 = (int)fminf(fmaxf(y1f, 0.f), (float)(H_-1));
            float w00 = (vy0 && vx0) ? wy0*wx0 : 0.f;
            float w01 = (vy0 && vx1) ? wy0*wx1 : 0.f;
            float w10 = (vy1 && vx0) ? wy1*wx0 : 0.f;
            float w11 = (vy1 && vx1) ? wy1*wx1 : 0.f;

            Meta mt;
            if (TR){
                uint sb = (uint)((b*F_ + f) * HW_);
                mt.a.x = (sb + (uint)(iy0*W_ + ix0)) << 8;   // *256B per pixel row
                mt.a.y = (sb + (uint)(iy0*W_ + ix1)) << 8;
                mt.a.z = (sb + (uint)(iy1*W_ + ix0)) << 8;
                mt.a.w = (sb + (uint)(iy1*W_ + ix1)) << 8;
            } else {
                uint sb = (uint)((b*F_ + f) * C_ * HW_);
                mt.a.x = (sb + (uint)(iy0*W_ + ix0)) << 2;   // f32 offsets
                mt.a.y = (sb + (uint)(iy0*W_ + ix1)) << 2;
                mt.a.z = (sb + (uint)(iy1*W_ + ix0)) << 2;
                mt.a.w = (sb + (uint)(iy1*W_ + ix1)) << 2;
            }
            mt.wd.x = dupf16(w00);
            mt.wd.y = dupf16(w01);
            mt.wd.z = dupf16(w10);
            mt.wd.w = dupf16(w11);
            mt.edge = (x >= 2.f && x <= (float)(W_-2) &&
                       y >= 2.f && y <= (float)(H_-2)) ? validf : 0.0f;
            mt.pad0 = mt.pad1 = mt.pad2 = 0.f;
            meta[wid][it] = mt;
        }
    }
    // same-wave LDS write->read: in-order wave + compiler waitcnt, no barrier needed

    // ---- cur channels for this lane ----
    f16x2 cur2;
    const char* ltb;
    const char* lk0;
    const char* lk1;
    if (TR){
        cur2 = asH2(*(const unsigned*)((const char*)CT +
                     (size_t)(b*HW_ + pix) * (C_*2) + lane*4));
        ltb = (const char*)LT + (size_t)lane * 4;
        lk0 = nullptr; lk1 = nullptr;
    } else {
        const float* cb = cur_f32 + (size_t)b * C_ * HW_ + pix;
        cur2 = pk2(cb[(size_t)(2*lane)*HW_], cb[(size_t)(2*lane+1)*HW_]);
        ltb = nullptr;
        lk0 = (const char*)look_f32 + (size_t)(2*lane) * HW_ * 4;
        lk1 = lk0 + (size_t)HW_ * 4;
    }

    float vmax = 0.f;
    float keep0 = 0.f, keep1 = 0.f;

#pragma unroll 2
    for (int d = 0; d < D_; ++d){
        float df[F_];
#pragma unroll
        for (int f = 0; f < F_; ++f){
            const Meta* m = &meta[wid][f*D_ + d];
            float edge = m->edge;          // wave-uniform broadcast
            float part;
            if (edge != 0.f){              // uniform branch
                uint4 aa = m->a;
                uint4 ww = m->wd;
                f16x2 t0, t1, t2, t3;
                if (TR){
                    t0 = asH2(*(const unsigned*)(ltb + aa.x));
                    t1 = asH2(*(const unsigned*)(ltb + aa.y));
                    t2 = asH2(*(const unsigned*)(ltb + aa.z));
                    t3 = asH2(*(const unsigned*)(ltb + aa.w));
                } else {
                    t0 = pk2(*(const float*)(lk0 + aa.x), *(const float*)(lk1 + aa.x));
                    t1 = pk2(*(const float*)(lk0 + aa.y), *(const float*)(lk1 + aa.y));
                    t2 = pk2(*(const float*)(lk0 + aa.z), *(const float*)(lk1 + aa.z));
                    t3 = pk2(*(const float*)(lk0 + aa.w), *(const float*)(lk1 + aa.w));
                }
                f16x2 s = t0*asH2(ww.x) + t1*asH2(ww.y)
                        + t2*asH2(ww.z) + t3*asH2(ww.w);
                part = sum2(habs2(s - cur2));
#pragma unroll
                for (int mm = 1; mm < 64; mm <<= 1)
                    part += __shfl_xor(part, mm);
                part = part * edge * (1.0f / C_);
            } else {
                part = 0.f;
            }
            df[f] = part;
        }
        float cnt = (df[0] > 0.f ? 1.f : 0.f) + (df[1] > 0.f ? 1.f : 0.f);
        float val = (df[0] + df[1]) / (cnt + EPS_);
        vmax = fmaxf(vmax, val);
        if (d == lane)      keep0 = val;
        if (d == 64 + lane) keep1 = val;
    }

    {
        float cv = (keep0 == 0.f) ? vmax : keep0;
        float mv = (keep0 == 0.f) ? 1.f : 0.f;
        out_cost[ob + (size_t)lane * HW_] = cv;
        out_missing[ob + (size_t)lane * HW_] = mv;
    }
    if (lane < 32){
        float cv = (keep1 == 0.f) ? vmax : keep1;
        float mv = (keep1 == 0.f) ? 1.f : 0.f;
        out_cost[ob + (size_t)(64 + lane) * HW_] = cv;
        out_missing[ob + (size_t)(64 + lane) * HW_] = mv;
    }
}

extern "C" void kernel_launch(void* const* d_in, const int* in_sizes, int n_in,
                              void* d_out, int out_size, void* d_ws, size_t ws_size,
                              hipStream_t stream){
    const float* cur   = (const float*)d_in[0];
    const float* look  = (const float*)d_in[1];
    const float* poses = (const float*)d_in[2];
    const float* Kmat  = (const float*)d_in[3];
    const float* invKm = (const float*)d_in[4];
    float* cost    = (float*)d_out;
    float* missing = cost + (size_t)B_ * D_ * HW_;

    const size_t ltBytes = (size_t)B_ * F_ * HW_ * C_ * 2;
    const size_t ctBytes = (size_t)B_ * HW_ * C_ * 2;
    const bool useTR = (ws_size >= ltBytes + ctBytes);
    const int nblocks = (B_ * HW_) / 4;    // one wave per pixel, 4 waves/block

    if (useTR){
        _Float16* LT = (_Float16*)d_ws;
        _Float16* CT = (_Float16*)((char*)d_ws + ltBytes);
        transpose_kernel<<<(B_*F_)*(C_/32)*(HW_/32), 256, 0, stream>>>(look, LT);
        transpose_kernel<<<B_*(C_/32)*(HW_/32), 256, 0, stream>>>(cur, CT);
        cost_kernel<true><<<nblocks, 256, 0, stream>>>(cur, look, poses, Kmat, invKm,
                                                       LT, CT, cost, missing);
    } else {
        cost_kernel<false><<<nblocks, 256, 0, stream>>>(cur, look, poses, Kmat, invKm,
                                                        nullptr, nullptr, cost, missing);
    }
}

// Round 4
// 152.775 us; speedup vs baseline: 3.2911x; 1.8972x over previous
//
#include <hip/hip_runtime.h>
#include <hip/hip_fp16.h>
#include <stdint.h>

#define B_ 2
#define F_ 2
#define C_ 128
#define D_ 96
#define H_ 48
#define W_ 128
#define HW_ (H_*W_)
#define EPS_ 1e-7f
#define RSTR 68

typedef _Float16 f16x2 __attribute__((ext_vector_type(2)));
typedef float f32x4 __attribute__((ext_vector_type(4)));
union U32H2 { unsigned u; f16x2 h; };

static __device__ __forceinline__ f16x2 asH2(unsigned u){ U32H2 t; t.u=u; return t.h; }
static __device__ __forceinline__ f16x2 habs2(f16x2 x){ U32H2 t; t.h=x; t.u&=0x7fff7fffu; return t.h; }

#if __has_builtin(__builtin_amdgcn_fdot2)
static __device__ __forceinline__ float sum2(f16x2 d){
    const f16x2 one = {(_Float16)1.0f, (_Float16)1.0f};
    return __builtin_amdgcn_fdot2(d, one, 0.0f, false);
}
#else
static __device__ __forceinline__ float sum2(f16x2 d){ return (float)d[0] + (float)d[1]; }
#endif

__device__ __forceinline__ float depth_bin(int d){
    return (float)(0.1 + (double)d * (19.9 / 95.0));
}

// transpose + f32->f16: src [nslice][C][HW] f32 -> dst [nslice][HW][C] f16
__global__ void transpose_kernel(const float* __restrict__ src,
                                 _Float16* __restrict__ dst){
    __shared__ float tile[32][33];
    const int tx = threadIdx.x & 31, ty = threadIdx.x >> 5;
    const int nc = C_ / 32;     // 4
    const int np = HW_ / 32;    // 192
    int bid = blockIdx.x;
    int p0 = (bid % np) * 32;
    int c0 = ((bid / np) % nc) * 32;
    int s  = bid / (np * nc);
    const float* sp = src + (size_t)s * C_ * HW_;
    _Float16* dp = dst + (size_t)s * HW_ * C_;
#pragma unroll
    for (int j = 0; j < 4; ++j){
        int c = c0 + ty + j * 8;
        tile[ty + j * 8][tx] = sp[(size_t)c * HW_ + p0 + tx];
    }
    __syncthreads();
#pragma unroll
    for (int j = 0; j < 4; ++j){
        int p = p0 + ty + j * 8;
        dp[(size_t)p * C_ + c0 + tx] = (_Float16)tile[tx][ty + j * 8];
    }
}

// one wave per output pixel; lane l covers channels 2l, 2l+1.
// slots: s = f*96+d, 0..191. Group g: slots g*64+lane computed per-lane into
// registers; inner loop broadcasts via v_readlane. Reduction: batched LDS
// transpose (16 slots/batch), double-buffered.
__global__ __launch_bounds__(256)
void cost_tr_kernel(const float* __restrict__ poses,
                    const float* __restrict__ Kmat,
                    const float* __restrict__ invKm,
                    const _Float16* __restrict__ LT,
                    const _Float16* __restrict__ CT,
                    float* __restrict__ out_cost,
                    float* __restrict__ out_missing)
{
    __shared__ __align__(16) float red[4][2][16][RSTR];

    const int wid  = threadIdx.x >> 6;
    const int lane = threadIdx.x & 63;
    const int pg   = blockIdx.x * 4 + wid;
    const int b    = pg / HW_;
    const int pix  = pg % HW_;
    const int h    = pix / W_;
    const int w    = pix % W_;
    const size_t ob = (size_t)b * D_ * HW_ + pix;

    // border fast path: whole column is cost=0, missing=1
    if (h < 2 || h > H_-3 || w < 2 || w > W_-3){
        out_cost[ob + (size_t)lane * HW_] = 0.f;
        out_missing[ob + (size_t)lane * HW_] = 1.f;
        if (lane < 32){
            out_cost[ob + (size_t)(64+lane) * HW_] = 0.f;
            out_missing[ob + (size_t)(64+lane) * HW_] = 1.f;
        }
        return;
    }

    // ---- projection setup for both frames (wave-uniform) ----
    float Qx[2], Qy[2], Qz[2], Tx[2], Ty[2], Tz[2], Vf[2];
    {
        const float* iK = invKm + b*16;
        const float u = (float)w, v = (float)h;
        const float dirx = iK[0]*u + iK[1]*v + iK[2];
        const float diry = iK[4]*u + iK[5]*v + iK[6];
        const float dirz = iK[8]*u + iK[9]*v + iK[10];
        const float* Kb = Kmat + b*16;
#pragma unroll
        for (int f = 0; f < 2; ++f){
            const float* ps = poses + ((size_t)b*F_ + f)*16;
            float psum = 0.f;
#pragma unroll
            for (int i = 0; i < 16; ++i) psum += ps[i];
            Vf[f] = (psum != 0.f) ? 1.f : 0.f;
            float P[3][4];
#pragma unroll
            for (int i = 0; i < 3; ++i)
#pragma unroll
                for (int j = 0; j < 4; ++j)
                    P[i][j] = Kb[i*4+0]*ps[j]    + Kb[i*4+1]*ps[4+j]
                            + Kb[i*4+2]*ps[8+j]  + Kb[i*4+3]*ps[12+j];
            Qx[f] = P[0][0]*dirx + P[0][1]*diry + P[0][2]*dirz;
            Qy[f] = P[1][0]*dirx + P[1][1]*diry + P[1][2]*dirz;
            Qz[f] = P[2][0]*dirx + P[2][1]*diry + P[2][2]*dirz;
            Tx[f] = P[0][3]; Ty[f] = P[1][3]; Tz[f] = P[2][3];
        }
    }

    const f16x2 cur2 = asH2(*(const unsigned*)((const char*)CT
                        + ((size_t)(b*HW_ + pix) * C_) * 2 + lane * 4));

    float sums0[6];
    float vals[6];
    float vmax = 0.f;
    float* redbase0 = &red[wid][0][0][0];
    float* redbase1 = &red[wid][1][0][0];

#pragma unroll
    for (int g = 0; g < 3; ++g){
        // this lane's slot meta (slot = g*64 + lane)
        unsigned mA, mW01, mW23;
        {
            int slot = g*64 + lane;
            int f = (slot >= 96) ? 1 : 0;
            int d = slot - 96*f;
            float dv = depth_bin(d);
            float qx = f ? Qx[1] : Qx[0];
            float qy = f ? Qy[1] : Qy[0];
            float qz = f ? Qz[1] : Qz[0];
            float tx = f ? Tx[1] : Tx[0];
            float ty = f ? Ty[1] : Ty[0];
            float tz = f ? Tz[1] : Tz[0];
            float vfl = f ? Vf[1] : Vf[0];
            float cz = qz*dv + tz + EPS_;
            float x = (qx*dv + tx) / cz;
            float y = (qy*dv + ty) / cz;
            // edge => strictly interior => no clamping/validity needed;
            // non-edge slots are skipped entirely.
            bool edge = (x >= 2.f) && (x <= (float)(W_-2)) &&
                        (y >= 2.f) && (y <= (float)(H_-2)) && (vfl != 0.f);
            float x0f = floorf(x), y0f = floorf(y);
            float wx1 = x - x0f, wy1 = y - y0f;
            float wx0 = 1.f - wx1, wy0 = 1.f - wy1;
            float xc = fminf(fmaxf(x0f, 0.f), (float)(W_-1));
            float yc = fminf(fmaxf(y0f, 0.f), (float)(H_-1));
            int ix0 = (int)xc, iy0 = (int)yc;
            int sb = (b*F_ + f) * HW_;
            mA = ((unsigned)(sb + iy0*W_ + ix0) << 8) | (edge ? 0x80000000u : 0u);
            U32H2 t;
            t.h[0] = (_Float16)(wy0*wx0); t.h[1] = (_Float16)(wy0*wx1);
            mW01 = t.u;
            t.h[0] = (_Float16)(wy1*wx0); t.h[1] = (_Float16)(wy1*wx1);
            mW23 = t.u;
        }

#pragma unroll
        for (int sbi = 0; sbi < 4; ++sbi){
            const int batch = g*4 + sbi;                 // 0..11 (static)
            float* redrow = (batch & 1) ? redbase1 : redbase0;
            float* wr = redrow + lane;
#pragma unroll 4
            for (int k = 0; k < 16; ++k){
                int l = sbi*16 + k;
                unsigned aE = (unsigned)__builtin_amdgcn_readlane((int)mA,   l);
                unsigned wA = (unsigned)__builtin_amdgcn_readlane((int)mW01, l);
                unsigned wB = (unsigned)__builtin_amdgcn_readlane((int)mW23, l);
                float part = 0.f;
                if (aE & 0x80000000u){                   // uniform branch
                    const char* p0 = (const char*)LT + (aE & 0x7fffffffu)
                                   + (unsigned)(lane * 4);
                    unsigned u0 = *(const unsigned*)(p0);
                    unsigned u1 = *(const unsigned*)(p0 + 256);
                    unsigned u2 = *(const unsigned*)(p0 + 256*W_);
                    unsigned u3 = *(const unsigned*)(p0 + 256*W_ + 256);
                    f16x2 hA = asH2(wA), hB = asH2(wB);
                    f16x2 w00 = {hA[0],hA[0]}, w01 = {hA[1],hA[1]};
                    f16x2 w10 = {hB[0],hB[0]}, w11 = {hB[1],hB[1]};
                    f16x2 s = asH2(u0)*w00 + asH2(u1)*w01
                            + asH2(u2)*w10 + asH2(u3)*w11;
                    part = sum2(habs2(s - cur2));
                }
                wr[k*RSTR] = part;
            }
            // batched reduce of 16 slots: lane sums quarter (lane&3) of slot (lane>>2)
            const float* rp = redrow + (lane>>2)*RSTR + (lane&3)*16;
            f32x4 r0 = *(const f32x4*)(rp);
            f32x4 r1 = *(const f32x4*)(rp+4);
            f32x4 r2 = *(const f32x4*)(rp+8);
            f32x4 r3 = *(const f32x4*)(rp+12);
            f32x4 rs = (r0+r1) + (r2+r3);
            float sq = (rs.x+rs.y) + (rs.z+rs.w);
            sq += __int_as_float(__builtin_amdgcn_ds_swizzle(__float_as_int(sq), 0x041F)); // ^1
            sq += __int_as_float(__builtin_amdgcn_ds_swizzle(__float_as_int(sq), 0x081F)); // ^2
            if (batch < 6){
                sums0[batch] = sq;
            } else {
                float df0 = sums0[batch-6] * (1.0f/C_);
                float df1 = sq * (1.0f/C_);
                float cnt = (df0 > 0.f ? 1.f : 0.f) + (df1 > 0.f ? 1.f : 0.f);
                float val = (df0 + df1) / (cnt + EPS_);
                vals[batch-6] = val;
                vmax = fmaxf(vmax, val);
            }
        }
    }

    // global max over all d: per-lane vmax covers dl = lane>>2 across batches
    vmax = fmaxf(vmax, __shfl_xor(vmax, 32));
    vmax = fmaxf(vmax, __int_as_float(__builtin_amdgcn_ds_swizzle(__float_as_int(vmax), 0x101F))); // ^4
    vmax = fmaxf(vmax, __int_as_float(__builtin_amdgcn_ds_swizzle(__float_as_int(vmax), 0x201F))); // ^8
    vmax = fmaxf(vmax, __int_as_float(__builtin_amdgcn_ds_swizzle(__float_as_int(vmax), 0x401F))); // ^16

    if ((lane & 3) == 0){
        const int dl = lane >> 2;
#pragma unroll
        for (int kk = 0; kk < 6; ++kk){
            float vv = vals[kk];
            size_t o = ob + (size_t)(kk*16 + dl) * HW_;
            out_cost[o]    = (vv == 0.f) ? vmax : vv;
            out_missing[o] = (vv == 0.f) ? 1.f : 0.f;
        }
    }
}

// naive correct fallback (one thread per pixel column) — only runs if ws too small
__global__ void cost_naive_kernel(const float* __restrict__ cur,
                                  const float* __restrict__ look,
                                  const float* __restrict__ poses,
                                  const float* __restrict__ Kmat,
                                  const float* __restrict__ invKm,
                                  float* __restrict__ out_cost,
                                  float* __restrict__ out_missing)
{
    int t = blockIdx.x * blockDim.x + threadIdx.x;
    if (t >= B_*HW_) return;
    int b = t / HW_, pix = t % HW_;
    int h = pix / W_, w = pix % W_;
    size_t ob = (size_t)b * D_ * HW_ + pix;
    bool border = (h >= 2 && h <= H_-3 && w >= 2 && w <= W_-3);
    const float* iK = invKm + b*16;
    float u = (float)w, v = (float)h;
    float dirx = iK[0]*u + iK[1]*v + iK[2];
    float diry = iK[4]*u + iK[5]*v + iK[6];
    float dirz = iK[8]*u + iK[9]*v + iK[10];
    const float* Kb = Kmat + b*16;
    float vmax = 0.f;
    for (int d = 0; d < D_; ++d){
        float dfs[2];
        for (int f = 0; f < 2; ++f){
            const float* ps = poses + ((size_t)b*F_ + f)*16;
            float psum = 0.f;
            for (int i = 0; i < 16; ++i) psum += ps[i];
            float vfl = (psum != 0.f) ? 1.f : 0.f;
            float P[3][4];
            for (int i = 0; i < 3; ++i)
                for (int j = 0; j < 4; ++j)
                    P[i][j] = Kb[i*4+0]*ps[j] + Kb[i*4+1]*ps[4+j]
                            + Kb[i*4+2]*ps[8+j] + Kb[i*4+3]*ps[12+j];
            float qx = P[0][0]*dirx + P[0][1]*diry + P[0][2]*dirz;
            float qy = P[1][0]*dirx + P[1][1]*diry + P[1][2]*dirz;
            float qz = P[2][0]*dirx + P[2][1]*diry + P[2][2]*dirz;
            float dv = depth_bin(d);
            float cz = qz*dv + P[2][3] + EPS_;
            float x = (qx*dv + P[0][3]) / cz;
            float y = (qy*dv + P[1][3]) / cz;
            bool edge = border && (x >= 2.f) && (x <= (float)(W_-2)) &&
                        (y >= 2.f) && (y <= (float)(H_-2)) && (vfl != 0.f);
            float part = 0.f;
            if (edge){
                float x0f = floorf(x), y0f = floorf(y);
                float wx1 = x - x0f, wy1 = y - y0f;
                float wx0 = 1.f - wx1, wy0 = 1.f - wy1;
                int ix0 = (int)x0f, iy0 = (int)y0f;
                const float* lb = look + (size_t)(b*F_+f) * C_ * HW_;
                const float* cb = cur + (size_t)b * C_ * HW_ + pix;
                int o00 = iy0*W_ + ix0;
                for (int c = 0; c < C_; ++c){
                    const float* lc = lb + (size_t)c * HW_;
                    float wv = wy0*wx0*lc[o00] + wy0*wx1*lc[o00+1]
                             + wy1*wx0*lc[o00+W_] + wy1*wx1*lc[o00+W_+1];
                    part += fabsf(wv - cb[(size_t)c * HW_]);
                }
                part *= (1.0f/C_);
            }
            dfs[f] = part;
        }
        float cnt = (dfs[0] > 0.f ? 1.f : 0.f) + (dfs[1] > 0.f ? 1.f : 0.f);
        float val = (dfs[0] + dfs[1]) / (cnt + EPS_);
        out_cost[ob + (size_t)d * HW_] = val;
        vmax = fmaxf(vmax, val);
    }
    for (int d = 0; d < D_; ++d){
        float vv = out_cost[ob + (size_t)d * HW_];
        out_missing[ob + (size_t)d * HW_] = (vv == 0.f) ? 1.f : 0.f;
        if (vv == 0.f) out_cost[ob + (size_t)d * HW_] = vmax;
    }
}

extern "C" void kernel_launch(void* const* d_in, const int* in_sizes, int n_in,
                              void* d_out, int out_size, void* d_ws, size_t ws_size,
                              hipStream_t stream){
    const float* cur   = (const float*)d_in[0];
    const float* look  = (const float*)d_in[1];
    const float* poses = (const float*)d_in[2];
    const float* Kmat  = (const float*)d_in[3];
    const float* invKm = (const float*)d_in[4];
    float* cost    = (float*)d_out;
    float* missing = cost + (size_t)B_ * D_ * HW_;

    const size_t ltBytes = (size_t)B_ * F_ * HW_ * C_ * 2;
    const size_t ctBytes = (size_t)B_ * HW_ * C_ * 2;
    const bool useTR = (ws_size >= ltBytes + ctBytes);

    if (useTR){
        _Float16* LT = (_Float16*)d_ws;
        _Float16* CT = (_Float16*)((char*)d_ws + ltBytes);
        transpose_kernel<<<(B_*F_)*(C_/32)*(HW_/32), 256, 0, stream>>>(look, LT);
        transpose_kernel<<<B_*(C_/32)*(HW_/32), 256, 0, stream>>>(cur, CT);
        cost_tr_kernel<<<(B_*HW_)/4, 256, 0, stream>>>(poses, Kmat, invKm,
                                                       LT, CT, cost, missing);
    } else {
        cost_naive_kernel<<<(B_*HW_ + 255)/256, 256, 0, stream>>>(
            cur, look, poses, Kmat, invKm, cost, missing);
    }
}

// Round 5
// 143.176 us; speedup vs baseline: 3.5117x; 1.0670x over previous
//
#include <hip/hip_runtime.h>
#include <hip/hip_fp16.h>
#include <stdint.h>

#define B_ 2
#define F_ 2
#define C_ 128
#define D_ 96
#define H_ 48
#define W_ 128
#define HW_ (H_*W_)
#define EPS_ 1e-7f
#define RSTR 68

typedef _Float16 f16x2 __attribute__((ext_vector_type(2)));
typedef float f32x4 __attribute__((ext_vector_type(4)));
union U32H2 { unsigned u; f16x2 h; };

static __device__ __forceinline__ f16x2 asH2(unsigned u){ U32H2 t; t.u=u; return t.h; }
static __device__ __forceinline__ f16x2 habs2(f16x2 x){ U32H2 t; t.h=x; t.u&=0x7fff7fffu; return t.h; }

#if __has_builtin(__builtin_amdgcn_fdot2)
static __device__ __forceinline__ float sum2(f16x2 d){
    const f16x2 one = {(_Float16)1.0f, (_Float16)1.0f};
    return __builtin_amdgcn_fdot2(d, one, 0.0f, false);
}
#else
static __device__ __forceinline__ float sum2(f16x2 d){ return (float)d[0] + (float)d[1]; }
#endif

__device__ __forceinline__ float depth_bin(int d){
    return (float)(0.1 + (double)d * (19.9 / 95.0));
}

// transpose + f32->f16: src [nslice][C][HW] f32 -> dst [nslice][HW][C] f16
__global__ void transpose_kernel(const float* __restrict__ src,
                                 _Float16* __restrict__ dst){
    __shared__ float tile[32][33];
    const int tx = threadIdx.x & 31, ty = threadIdx.x >> 5;
    const int nc = C_ / 32;     // 4
    const int np = HW_ / 32;    // 192
    int bid = blockIdx.x;
    int p0 = (bid % np) * 32;
    int c0 = ((bid / np) % nc) * 32;
    int s  = bid / (np * nc);
    const float* sp = src + (size_t)s * C_ * HW_;
    _Float16* dp = dst + (size_t)s * HW_ * C_;
#pragma unroll
    for (int j = 0; j < 4; ++j){
        int c = c0 + ty + j * 8;
        tile[ty + j * 8][tx] = sp[(size_t)c * HW_ + p0 + tx];
    }
    __syncthreads();
#pragma unroll
    for (int j = 0; j < 4; ++j){
        int p = p0 + ty + j * 8;
        dp[(size_t)p * C_ + c0 + tx] = (_Float16)tile[tx][ty + j * 8];
    }
}

// one wave per output pixel; lane l covers channels 2l, 2l+1.
// slots: s = f*96+d, 0..191. Group g: slots g*64+lane computed per-lane into
// registers; inner loop broadcasts via v_readlane. Reduction: batched LDS
// transpose (16 slots/batch). Single LDS buffer: DS ops from one wave execute
// in order, so write->read and read->overwrite hazards within the wave are safe
// (empirically confirmed: R4 relied on the same ordering for RAW).
__global__ __launch_bounds__(256, 8)
void cost_tr_kernel(const float* __restrict__ poses,
                    const float* __restrict__ Kmat,
                    const float* __restrict__ invKm,
                    const _Float16* __restrict__ LT,
                    const _Float16* __restrict__ CT,
                    float* __restrict__ out_cost,
                    float* __restrict__ out_missing)
{
    __shared__ __align__(16) float red[4][16][RSTR];   // 17408 B -> 8 blocks/CU

    const int wid  = threadIdx.x >> 6;
    const int lane = threadIdx.x & 63;
    const int pg   = blockIdx.x * 4 + wid;
    const int b    = pg / HW_;
    const int pix  = pg % HW_;
    const int h    = pix / W_;
    const int w    = pix % W_;
    const size_t ob = (size_t)b * D_ * HW_ + pix;

    // border fast path: whole column is cost=0, missing=1
    if (h < 2 || h > H_-3 || w < 2 || w > W_-3){
        out_cost[ob + (size_t)lane * HW_] = 0.f;
        out_missing[ob + (size_t)lane * HW_] = 1.f;
        if (lane < 32){
            out_cost[ob + (size_t)(64+lane) * HW_] = 0.f;
            out_missing[ob + (size_t)(64+lane) * HW_] = 1.f;
        }
        return;
    }

    // ---- projection setup for both frames (wave-uniform) ----
    float Qx[2], Qy[2], Qz[2], Tx[2], Ty[2], Tz[2], Vf[2];
    {
        const float* iK = invKm + b*16;
        const float u = (float)w, v = (float)h;
        const float dirx = iK[0]*u + iK[1]*v + iK[2];
        const float diry = iK[4]*u + iK[5]*v + iK[6];
        const float dirz = iK[8]*u + iK[9]*v + iK[10];
        const float* Kb = Kmat + b*16;
#pragma unroll
        for (int f = 0; f < 2; ++f){
            const float* ps = poses + ((size_t)b*F_ + f)*16;
            float psum = 0.f;
#pragma unroll
            for (int i = 0; i < 16; ++i) psum += ps[i];
            Vf[f] = (psum != 0.f) ? 1.f : 0.f;
            float P[3][4];
#pragma unroll
            for (int i = 0; i < 3; ++i)
#pragma unroll
                for (int j = 0; j < 4; ++j)
                    P[i][j] = Kb[i*4+0]*ps[j]    + Kb[i*4+1]*ps[4+j]
                            + Kb[i*4+2]*ps[8+j]  + Kb[i*4+3]*ps[12+j];
            Qx[f] = P[0][0]*dirx + P[0][1]*diry + P[0][2]*dirz;
            Qy[f] = P[1][0]*dirx + P[1][1]*diry + P[1][2]*dirz;
            Qz[f] = P[2][0]*dirx + P[2][1]*diry + P[2][2]*dirz;
            Tx[f] = P[0][3]; Ty[f] = P[1][3]; Tz[f] = P[2][3];
        }
    }

    const f16x2 cur2 = asH2(*(const unsigned*)((const char*)CT
                        + ((size_t)(b*HW_ + pix) * C_) * 2 + lane * 4));

    float sums0[6];
    float vals[6];
    float vmax = 0.f;
    float* redbase = &red[wid][0][0];

#pragma unroll
    for (int g = 0; g < 3; ++g){
        // this lane's slot meta (slot = g*64 + lane)
        unsigned mA, mW01, mW23;
        {
            int slot = g*64 + lane;
            int f = (slot >= 96) ? 1 : 0;
            int d = slot - 96*f;
            float dv = depth_bin(d);
            float qx = f ? Qx[1] : Qx[0];
            float qy = f ? Qy[1] : Qy[0];
            float qz = f ? Qz[1] : Qz[0];
            float tx = f ? Tx[1] : Tx[0];
            float ty = f ? Ty[1] : Ty[0];
            float tz = f ? Tz[1] : Tz[0];
            float vfl = f ? Vf[1] : Vf[0];
            float cz = qz*dv + tz + EPS_;
            float x = (qx*dv + tx) / cz;
            float y = (qy*dv + ty) / cz;
            // edge => strictly interior => no clamping/validity needed;
            // non-edge slots are skipped entirely.
            bool edge = (x >= 2.f) && (x <= (float)(W_-2)) &&
                        (y >= 2.f) && (y <= (float)(H_-2)) && (vfl != 0.f);
            float x0f = floorf(x), y0f = floorf(y);
            float wx1 = x - x0f, wy1 = y - y0f;
            float wx0 = 1.f - wx1, wy0 = 1.f - wy1;
            float xc = fminf(fmaxf(x0f, 0.f), (float)(W_-1));
            float yc = fminf(fmaxf(y0f, 0.f), (float)(H_-1));
            int ix0 = (int)xc, iy0 = (int)yc;
            int sb = (b*F_ + f) * HW_;
            mA = ((unsigned)(sb + iy0*W_ + ix0) << 8) | (edge ? 0x80000000u : 0u);
            U32H2 t;
            t.h[0] = (_Float16)(wy0*wx0); t.h[1] = (_Float16)(wy0*wx1);
            mW01 = t.u;
            t.h[0] = (_Float16)(wy1*wx0); t.h[1] = (_Float16)(wy1*wx1);
            mW23 = t.u;
        }

#pragma unroll
        for (int sbi = 0; sbi < 4; ++sbi){
            const int batch = g*4 + sbi;                 // 0..11 (static)
            float* wr = redbase + lane;
#pragma unroll 4
            for (int k = 0; k < 16; ++k){
                int l = sbi*16 + k;
                unsigned aE = (unsigned)__builtin_amdgcn_readlane((int)mA,   l);
                unsigned wA = (unsigned)__builtin_amdgcn_readlane((int)mW01, l);
                unsigned wB = (unsigned)__builtin_amdgcn_readlane((int)mW23, l);
                float part = 0.f;
                if (aE & 0x80000000u){                   // uniform branch
                    const char* p0 = (const char*)LT + (aE & 0x7fffffffu)
                                   + (unsigned)(lane * 4);
                    unsigned u0 = *(const unsigned*)(p0);
                    unsigned u1 = *(const unsigned*)(p0 + 256);
                    unsigned u2 = *(const unsigned*)(p0 + 256*W_);
                    unsigned u3 = *(const unsigned*)(p0 + 256*W_ + 256);
                    f16x2 hA = asH2(wA), hB = asH2(wB);
                    f16x2 w00 = {hA[0],hA[0]}, w01 = {hA[1],hA[1]};
                    f16x2 w10 = {hB[0],hB[0]}, w11 = {hB[1],hB[1]};
                    f16x2 s = asH2(u0)*w00 + asH2(u1)*w01
                            + asH2(u2)*w10 + asH2(u3)*w11;
                    part = sum2(habs2(s - cur2));
                }
                wr[k*RSTR] = part;
            }
            // batched reduce of 16 slots: lane sums quarter (lane&3) of slot (lane>>2)
            const float* rp = redbase + (lane>>2)*RSTR + (lane&3)*16;
            f32x4 r0 = *(const f32x4*)(rp);
            f32x4 r1 = *(const f32x4*)(rp+4);
            f32x4 r2 = *(const f32x4*)(rp+8);
            f32x4 r3 = *(const f32x4*)(rp+12);
            f32x4 rs = (r0+r1) + (r2+r3);
            float sq = (rs.x+rs.y) + (rs.z+rs.w);
            sq += __int_as_float(__builtin_amdgcn_ds_swizzle(__float_as_int(sq), 0x041F)); // ^1
            sq += __int_as_float(__builtin_amdgcn_ds_swizzle(__float_as_int(sq), 0x081F)); // ^2
            if (batch < 6){
                sums0[batch] = sq;
            } else {
                float df0 = sums0[batch-6] * (1.0f/C_);
                float df1 = sq * (1.0f/C_);
                float cnt = (df0 > 0.f ? 1.f : 0.f) + (df1 > 0.f ? 1.f : 0.f);
                float val = (df0 + df1) / (cnt + EPS_);
                vals[batch-6] = val;
                vmax = fmaxf(vmax, val);
            }
        }
    }

    // global max over all d: per-lane vmax covers dl = lane>>2 across batches
    vmax = fmaxf(vmax, __shfl_xor(vmax, 32));
    vmax = fmaxf(vmax, __int_as_float(__builtin_amdgcn_ds_swizzle(__float_as_int(vmax), 0x101F))); // ^4
    vmax = fmaxf(vmax, __int_as_float(__builtin_amdgcn_ds_swizzle(__float_as_int(vmax), 0x201F))); // ^8
    vmax = fmaxf(vmax, __int_as_float(__builtin_amdgcn_ds_swizzle(__float_as_int(vmax), 0x401F))); // ^16

    if ((lane & 3) == 0){
        const int dl = lane >> 2;
#pragma unroll
        for (int kk = 0; kk < 6; ++kk){
            float vv = vals[kk];
            size_t o = ob + (size_t)(kk*16 + dl) * HW_;
            out_cost[o]    = (vv == 0.f) ? vmax : vv;
            out_missing[o] = (vv == 0.f) ? 1.f : 0.f;
        }
    }
}

// naive correct fallback (one thread per pixel column) — only runs if ws too small
__global__ void cost_naive_kernel(const float* __restrict__ cur,
                                  const float* __restrict__ look,
                                  const float* __restrict__ poses,
                                  const float* __restrict__ Kmat,
                                  const float* __restrict__ invKm,
                                  float* __restrict__ out_cost,
                                  float* __restrict__ out_missing)
{
    int t = blockIdx.x * blockDim.x + threadIdx.x;
    if (t >= B_*HW_) return;
    int b = t / HW_, pix = t % HW_;
    int h = pix / W_, w = pix % W_;
    size_t ob = (size_t)b * D_ * HW_ + pix;
    bool border = (h >= 2 && h <= H_-3 && w >= 2 && w <= W_-3);
    const float* iK = invKm + b*16;
    float u = (float)w, v = (float)h;
    float dirx = iK[0]*u + iK[1]*v + iK[2];
    float diry = iK[4]*u + iK[5]*v + iK[6];
    float dirz = iK[8]*u + iK[9]*v + iK[10];
    const float* Kb = Kmat + b*16;
    float vmax = 0.f;
    for (int d = 0; d < D_; ++d){
        float dfs[2];
        for (int f = 0; f < 2; ++f){
            const float* ps = poses + ((size_t)b*F_ + f)*16;
            float psum = 0.f;
            for (int i = 0; i < 16; ++i) psum += ps[i];
            float vfl = (psum != 0.f) ? 1.f : 0.f;
            float P[3][4];
            for (int i = 0; i < 3; ++i)
                for (int j = 0; j < 4; ++j)
                    P[i][j] = Kb[i*4+0]*ps[j] + Kb[i*4+1]*ps[4+j]
                            + Kb[i*4+2]*ps[8+j] + Kb[i*4+3]*ps[12+j];
            float qx = P[0][0]*dirx + P[0][1]*diry + P[0][2]*dirz;
            float qy = P[1][0]*dirx + P[1][1]*diry + P[1][2]*dirz;
            float qz = P[2][0]*dirx + P[2][1]*diry + P[2][2]*dirz;
            float dv = depth_bin(d);
            float cz = qz*dv + P[2][3] + EPS_;
            float x = (qx*dv + P[0][3]) / cz;
            float y = (qy*dv + P[1][3]) / cz;
            bool edge = border && (x >= 2.f) && (x <= (float)(W_-2)) &&
                        (y >= 2.f) && (y <= (float)(H_-2)) && (vfl != 0.f);
            float part = 0.f;
            if (edge){
                float x0f = floorf(x), y0f = floorf(y);
                float wx1 = x - x0f, wy1 = y - y0f;
                float wx0 = 1.f - wx1, wy0 = 1.f - wy1;
                int ix0 = (int)x0f, iy0 = (int)y0f;
                const float* lb = look + (size_t)(b*F_+f) * C_ * HW_;
                const float* cb = cur + (size_t)b * C_ * HW_ + pix;
                int o00 = iy0*W_ + ix0;
                for (int c = 0; c < C_; ++c){
                    const float* lc = lb + (size_t)c * HW_;
                    float wv = wy0*wx0*lc[o00] + wy0*wx1*lc[o00+1]
                             + wy1*wx0*lc[o00+W_] + wy1*wx1*lc[o00+W_+1];
                    part += fabsf(wv - cb[(size_t)c * HW_]);
                }
                part *= (1.0f/C_);
            }
            dfs[f] = part;
        }
        float cnt = (dfs[0] > 0.f ? 1.f : 0.f) + (dfs[1] > 0.f ? 1.f : 0.f);
        float val = (dfs[0] + dfs[1]) / (cnt + EPS_);
        out_cost[ob + (size_t)d * HW_] = val;
        vmax = fmaxf(vmax, val);
    }
    for (int d = 0; d < D_; ++d){
        float vv = out_cost[ob + (size_t)d * HW_];
        out_missing[ob + (size_t)d * HW_] = (vv == 0.f) ? 1.f : 0.f;
        if (vv == 0.f) out_cost[ob + (size_t)d * HW_] = vmax;
    }
}

extern "C" void kernel_launch(void* const* d_in, const int* in_sizes, int n_in,
                              void* d_out, int out_size, void* d_ws, size_t ws_size,
                              hipStream_t stream){
    const float* cur   = (const float*)d_in[0];
    const float* look  = (const float*)d_in[1];
    const float* poses = (const float*)d_in[2];
    const float* Kmat  = (const float*)d_in[3];
    const float* invKm = (const float*)d_in[4];
    float* cost    = (float*)d_out;
    float* missing = cost + (size_t)B_ * D_ * HW_;

    const size_t ltBytes = (size_t)B_ * F_ * HW_ * C_ * 2;
    const size_t ctBytes = (size_t)B_ * HW_ * C_ * 2;
    const bool useTR = (ws_size >= ltBytes + ctBytes);

    if (useTR){
        _Float16* LT = (_Float16*)d_ws;
        _Float16* CT = (_Float16*)((char*)d_ws + ltBytes);
        transpose_kernel<<<(B_*F_)*(C_/32)*(HW_/32), 256, 0, stream>>>(look, LT);
        transpose_kernel<<<B_*(C_/32)*(HW_/32), 256, 0, stream>>>(cur, CT);
        cost_tr_kernel<<<(B_*HW_)/4, 256, 0, stream>>>(poses, Kmat, invKm,
                                                       LT, CT, cost, missing);
    } else {
        cost_naive_kernel<<<(B_*HW_ + 255)/256, 256, 0, stream>>>(
            cur, look, poses, Kmat, invKm, cost, missing);
    }
}

// Round 6
// 127.810 us; speedup vs baseline: 3.9339x; 1.1202x over previous
//
#include <hip/hip_runtime.h>
#include <hip/hip_fp16.h>
#include <stdint.h>

#define B_ 2
#define F_ 2
#define C_ 128
#define D_ 96
#define H_ 48
#define W_ 128
#define HW_ (H_*W_)
#define EPS_ 1e-7f
#define RSTR 68

typedef _Float16 f16x2 __attribute__((ext_vector_type(2)));
typedef float f32x4 __attribute__((ext_vector_type(4)));
union U32H2 { unsigned u; f16x2 h; };

static __device__ __forceinline__ f16x2 asH2(unsigned u){ U32H2 t; t.u=u; return t.h; }
static __device__ __forceinline__ f16x2 habs2(f16x2 x){ U32H2 t; t.h=x; t.u&=0x7fff7fffu; return t.h; }

#if __has_builtin(__builtin_amdgcn_fdot2)
static __device__ __forceinline__ float sum2(f16x2 d){
    const f16x2 one = {(_Float16)1.0f, (_Float16)1.0f};
    return __builtin_amdgcn_fdot2(d, one, 0.0f, false);
}
#else
static __device__ __forceinline__ float sum2(f16x2 d){ return (float)d[0] + (float)d[1]; }
#endif

__device__ __forceinline__ float depth_bin(int d){
    return (float)(0.1 + (double)d * (19.9 / 95.0));
}

// transpose + f32->f16: src [nslice][C][HW] f32 -> dst [nslice][HW][C] f16
__global__ void transpose_kernel(const float* __restrict__ src,
                                 _Float16* __restrict__ dst){
    __shared__ float tile[32][33];
    const int tx = threadIdx.x & 31, ty = threadIdx.x >> 5;
    const int nc = C_ / 32;     // 4
    const int np = HW_ / 32;    // 192
    int bid = blockIdx.x;
    int p0 = (bid % np) * 32;
    int c0 = ((bid / np) % nc) * 32;
    int s  = bid / (np * nc);
    const float* sp = src + (size_t)s * C_ * HW_;
    _Float16* dp = dst + (size_t)s * HW_ * C_;
#pragma unroll
    for (int j = 0; j < 4; ++j){
        int c = c0 + ty + j * 8;
        tile[ty + j * 8][tx] = sp[(size_t)c * HW_ + p0 + tx];
    }
    __syncthreads();
#pragma unroll
    for (int j = 0; j < 4; ++j){
        int p = p0 + ty + j * 8;
        dp[(size_t)p * C_ + c0 + tx] = (_Float16)tile[tx][ty + j * 8];
    }
}

// one wave per output pixel; lane l covers channels 2l, 2l+1.
// slots: s = f*96+d, 0..191. Group g: slots g*64+lane computed per-lane into
// registers; inner loop broadcasts via v_readlane. Reduction: batched LDS
// transpose (16 slots/batch). Single LDS buffer: DS ops from one wave execute
// in order, so intra-wave RAW/WAR through LDS are safe (empirically confirmed
// R4/R5). Inner loop is BRANCHLESS: loads always execute (addresses are
// clamped in-range), edge-mask applied as a bitwise AND — this lets the
// compiler batch all 16 loads of an unrolled group before one vmcnt wait.
__global__ __launch_bounds__(256, 8)
void cost_tr_kernel(const float* __restrict__ poses,
                    const float* __restrict__ Kmat,
                    const float* __restrict__ invKm,
                    const _Float16* __restrict__ LT,
                    const _Float16* __restrict__ CT,
                    float* __restrict__ out_cost,
                    float* __restrict__ out_missing)
{
    __shared__ __align__(16) float red[4][16][RSTR];   // 17408 B -> 8 blocks/CU

    const int wid  = threadIdx.x >> 6;
    const int lane = threadIdx.x & 63;
    const int pg   = blockIdx.x * 4 + wid;
    const int b    = pg / HW_;
    const int pix  = pg % HW_;
    const int h    = pix / W_;
    const int w    = pix % W_;
    const size_t ob = (size_t)b * D_ * HW_ + pix;

    // border fast path: whole column is cost=0, missing=1
    if (h < 2 || h > H_-3 || w < 2 || w > W_-3){
        out_cost[ob + (size_t)lane * HW_] = 0.f;
        out_missing[ob + (size_t)lane * HW_] = 1.f;
        if (lane < 32){
            out_cost[ob + (size_t)(64+lane) * HW_] = 0.f;
            out_missing[ob + (size_t)(64+lane) * HW_] = 1.f;
        }
        return;
    }

    // ---- projection setup for both frames (wave-uniform) ----
    float Qx[2], Qy[2], Qz[2], Tx[2], Ty[2], Tz[2], Vf[2];
    {
        const float* iK = invKm + b*16;
        const float u = (float)w, v = (float)h;
        const float dirx = iK[0]*u + iK[1]*v + iK[2];
        const float diry = iK[4]*u + iK[5]*v + iK[6];
        const float dirz = iK[8]*u + iK[9]*v + iK[10];
        const float* Kb = Kmat + b*16;
#pragma unroll
        for (int f = 0; f < 2; ++f){
            const float* ps = poses + ((size_t)b*F_ + f)*16;
            float psum = 0.f;
#pragma unroll
            for (int i = 0; i < 16; ++i) psum += ps[i];
            Vf[f] = (psum != 0.f) ? 1.f : 0.f;
            float P[3][4];
#pragma unroll
            for (int i = 0; i < 3; ++i)
#pragma unroll
                for (int j = 0; j < 4; ++j)
                    P[i][j] = Kb[i*4+0]*ps[j]    + Kb[i*4+1]*ps[4+j]
                            + Kb[i*4+2]*ps[8+j]  + Kb[i*4+3]*ps[12+j];
            Qx[f] = P[0][0]*dirx + P[0][1]*diry + P[0][2]*dirz;
            Qy[f] = P[1][0]*dirx + P[1][1]*diry + P[1][2]*dirz;
            Qz[f] = P[2][0]*dirx + P[2][1]*diry + P[2][2]*dirz;
            Tx[f] = P[0][3]; Ty[f] = P[1][3]; Tz[f] = P[2][3];
        }
    }

    const f16x2 cur2 = asH2(*(const unsigned*)((const char*)CT
                        + ((size_t)(b*HW_ + pix) * C_) * 2 + lane * 4));

    float sums0[6];
    float vals[6];
    float vmax = 0.f;
    float* redbase = &red[wid][0][0];
    const unsigned lane4 = (unsigned)(lane * 4);

#pragma unroll
    for (int g = 0; g < 3; ++g){
        // this lane's slot meta (slot = g*64 + lane)
        unsigned mA, mW01, mW23;
        {
            int slot = g*64 + lane;
            int f = (slot >= 96) ? 1 : 0;
            int d = slot - 96*f;
            float dv = depth_bin(d);
            float qx = f ? Qx[1] : Qx[0];
            float qy = f ? Qy[1] : Qy[0];
            float qz = f ? Qz[1] : Qz[0];
            float tx = f ? Tx[1] : Tx[0];
            float ty = f ? Ty[1] : Ty[0];
            float tz = f ? Tz[1] : Tz[0];
            float vfl = f ? Vf[1] : Vf[0];
            float cz = qz*dv + tz + EPS_;
            float x = (qx*dv + tx) / cz;
            float y = (qy*dv + ty) / cz;
            // edge => strictly interior => no clamping/validity needed;
            // non-edge slots contribute exactly 0 (mask below).
            bool edge = (x >= 2.f) && (x <= (float)(W_-2)) &&
                        (y >= 2.f) && (y <= (float)(H_-2)) && (vfl != 0.f);
            float x0f = floorf(x), y0f = floorf(y);
            float wx1 = x - x0f, wy1 = y - y0f;
            float wx0 = 1.f - wx1, wy0 = 1.f - wy1;
            float xc = fminf(fmaxf(x0f, 0.f), (float)(W_-1));
            float yc = fminf(fmaxf(y0f, 0.f), (float)(H_-1));
            int ix0 = (int)xc, iy0 = (int)yc;
            int sb = (b*F_ + f) * HW_;
            mA = ((unsigned)(sb + iy0*W_ + ix0) << 8) | (edge ? 0x80000000u : 0u);
            U32H2 t;
            t.h[0] = (_Float16)(wy0*wx0); t.h[1] = (_Float16)(wy0*wx1);
            mW01 = t.u;
            t.h[0] = (_Float16)(wy1*wx0); t.h[1] = (_Float16)(wy1*wx1);
            mW23 = t.u;
        }

#pragma unroll
        for (int sbi = 0; sbi < 4; ++sbi){
            const int batch = g*4 + sbi;                 // 0..11 (static)
            float* wr = redbase + lane;
#pragma unroll 4
            for (int k = 0; k < 16; ++k){
                int l = sbi*16 + k;
                unsigned aE = (unsigned)__builtin_amdgcn_readlane((int)mA,   l);
                unsigned wA = (unsigned)__builtin_amdgcn_readlane((int)mW01, l);
                unsigned wB = (unsigned)__builtin_amdgcn_readlane((int)mW23, l);
                // branchless: loads always execute (address clamped in-range)
                const char* p0 = (const char*)LT + (aE & 0x7fffff00u) + lane4;
                unsigned u0 = *(const unsigned*)(p0);
                unsigned u1 = *(const unsigned*)(p0 + 256);
                unsigned u2 = *(const unsigned*)(p0 + 256*W_);
                unsigned u3 = *(const unsigned*)(p0 + 256*W_ + 256);
                f16x2 hA = asH2(wA), hB = asH2(wB);
                f16x2 w00 = {hA[0],hA[0]}, w01 = {hA[1],hA[1]};
                f16x2 w10 = {hB[0],hB[0]}, w11 = {hB[1],hB[1]};
                f16x2 s = asH2(u0)*w00 + asH2(u1)*w01
                        + asH2(u2)*w10 + asH2(u3)*w11;
                float part = sum2(habs2(s - cur2));
                // edge mask: (int)aE>>31 = all-ones iff edge bit set
                unsigned msk = (unsigned)((int)aE >> 31);
                part = __uint_as_float(__float_as_uint(part) & msk);
                wr[k*RSTR] = part;
            }
            // batched reduce of 16 slots: lane sums quarter (lane&3) of slot (lane>>2)
            const float* rp = redbase + (lane>>2)*RSTR + (lane&3)*16;
            f32x4 r0 = *(const f32x4*)(rp);
            f32x4 r1 = *(const f32x4*)(rp+4);
            f32x4 r2 = *(const f32x4*)(rp+8);
            f32x4 r3 = *(const f32x4*)(rp+12);
            f32x4 rs = (r0+r1) + (r2+r3);
            float sq = (rs.x+rs.y) + (rs.z+rs.w);
            sq += __int_as_float(__builtin_amdgcn_ds_swizzle(__float_as_int(sq), 0x041F)); // ^1
            sq += __int_as_float(__builtin_amdgcn_ds_swizzle(__float_as_int(sq), 0x081F)); // ^2
            if (batch < 6){
                sums0[batch] = sq;
            } else {
                float df0 = sums0[batch-6] * (1.0f/C_);
                float df1 = sq * (1.0f/C_);
                float cnt = (df0 > 0.f ? 1.f : 0.f) + (df1 > 0.f ? 1.f : 0.f);
                float val = (df0 + df1) / (cnt + EPS_);
                vals[batch-6] = val;
                vmax = fmaxf(vmax, val);
            }
        }
    }

    // global max over all d: per-lane vmax covers dl = lane>>2 across batches
    vmax = fmaxf(vmax, __shfl_xor(vmax, 32));
    vmax = fmaxf(vmax, __int_as_float(__builtin_amdgcn_ds_swizzle(__float_as_int(vmax), 0x101F))); // ^4
    vmax = fmaxf(vmax, __int_as_float(__builtin_amdgcn_ds_swizzle(__float_as_int(vmax), 0x201F))); // ^8
    vmax = fmaxf(vmax, __int_as_float(__builtin_amdgcn_ds_swizzle(__float_as_int(vmax), 0x401F))); // ^16

    if ((lane & 3) == 0){
        const int dl = lane >> 2;
#pragma unroll
        for (int kk = 0; kk < 6; ++kk){
            float vv = vals[kk];
            size_t o = ob + (size_t)(kk*16 + dl) * HW_;
            out_cost[o]    = (vv == 0.f) ? vmax : vv;
            out_missing[o] = (vv == 0.f) ? 1.f : 0.f;
        }
    }
}

// naive correct fallback (one thread per pixel column) — only runs if ws too small
__global__ void cost_naive_kernel(const float* __restrict__ cur,
                                  const float* __restrict__ look,
                                  const float* __restrict__ poses,
                                  const float* __restrict__ Kmat,
                                  const float* __restrict__ invKm,
                                  float* __restrict__ out_cost,
                                  float* __restrict__ out_missing)
{
    int t = blockIdx.x * blockDim.x + threadIdx.x;
    if (t >= B_*HW_) return;
    int b = t / HW_, pix = t % HW_;
    int h = pix / W_, w = pix % W_;
    size_t ob = (size_t)b * D_ * HW_ + pix;
    bool border = (h >= 2 && h <= H_-3 && w >= 2 && w <= W_-3);
    const float* iK = invKm + b*16;
    float u = (float)w, v = (float)h;
    float dirx = iK[0]*u + iK[1]*v + iK[2];
    float diry = iK[4]*u + iK[5]*v + iK[6];
    float dirz = iK[8]*u + iK[9]*v + iK[10];
    const float* Kb = Kmat + b*16;
    float vmax = 0.f;
    for (int d = 0; d < D_; ++d){
        float dfs[2];
        for (int f = 0; f < 2; ++f){
            const float* ps = poses + ((size_t)b*F_ + f)*16;
            float psum = 0.f;
            for (int i = 0; i < 16; ++i) psum += ps[i];
            float vfl = (psum != 0.f) ? 1.f : 0.f;
            float P[3][4];
            for (int i = 0; i < 3; ++i)
                for (int j = 0; j < 4; ++j)
                    P[i][j] = Kb[i*4+0]*ps[j] + Kb[i*4+1]*ps[4+j]
                            + Kb[i*4+2]*ps[8+j] + Kb[i*4+3]*ps[12+j];
            float qx = P[0][0]*dirx + P[0][1]*diry + P[0][2]*dirz;
            float qy = P[1][0]*dirx + P[1][1]*diry + P[1][2]*dirz;
            float qz = P[2][0]*dirx + P[2][1]*diry + P[2][2]*dirz;
            float dv = depth_bin(d);
            float cz = qz*dv + P[2][3] + EPS_;
            float x = (qx*dv + P[0][3]) / cz;
            float y = (qy*dv + P[1][3]) / cz;
            bool edge = border && (x >= 2.f) && (x <= (float)(W_-2)) &&
                        (y >= 2.f) && (y <= (float)(H_-2)) && (vfl != 0.f);
            float part = 0.f;
            if (edge){
                float x0f = floorf(x), y0f = floorf(y);
                float wx1 = x - x0f, wy1 = y - y0f;
                float wx0 = 1.f - wx1, wy0 = 1.f - wy1;
                int ix0 = (int)x0f, iy0 = (int)y0f;
                const float* lb = look + (size_t)(b*F_+f) * C_ * HW_;
                const float* cb = cur + (size_t)b * C_ * HW_ + pix;
                int o00 = iy0*W_ + ix0;
                for (int c = 0; c < C_; ++c){
                    const float* lc = lb + (size_t)c * HW_;
                    float wv = wy0*wx0*lc[o00] + wy0*wx1*lc[o00+1]
                             + wy1*wx0*lc[o00+W_] + wy1*wx1*lc[o00+W_+1];
                    part += fabsf(wv - cb[(size_t)c * HW_]);
                }
                part *= (1.0f/C_);
            }
            dfs[f] = part;
        }
        float cnt = (dfs[0] > 0.f ? 1.f : 0.f) + (dfs[1] > 0.f ? 1.f : 0.f);
        float val = (dfs[0] + dfs[1]) / (cnt + EPS_);
        out_cost[ob + (size_t)d * HW_] = val;
        vmax = fmaxf(vmax, val);
    }
    for (int d = 0; d < D_; ++d){
        float vv = out_cost[ob + (size_t)d * HW_];
        out_missing[ob + (size_t)d * HW_] = (vv == 0.f) ? 1.f : 0.f;
        if (vv == 0.f) out_cost[ob + (size_t)d * HW_] = vmax;
    }
}

extern "C" void kernel_launch(void* const* d_in, const int* in_sizes, int n_in,
                              void* d_out, int out_size, void* d_ws, size_t ws_size,
                              hipStream_t stream){
    const float* cur   = (const float*)d_in[0];
    const float* look  = (const float*)d_in[1];
    const float* poses = (const float*)d_in[2];
    const float* Kmat  = (const float*)d_in[3];
    const float* invKm = (const float*)d_in[4];
    float* cost    = (float*)d_out;
    float* missing = cost + (size_t)B_ * D_ * HW_;

    const size_t ltBytes = (size_t)B_ * F_ * HW_ * C_ * 2;
    const size_t ctBytes = (size_t)B_ * HW_ * C_ * 2;
    const bool useTR = (ws_size >= ltBytes + ctBytes);

    if (useTR){
        _Float16* LT = (_Float16*)d_ws;
        _Float16* CT = (_Float16*)((char*)d_ws + ltBytes);
        transpose_kernel<<<(B_*F_)*(C_/32)*(HW_/32), 256, 0, stream>>>(look, LT);
        transpose_kernel<<<B_*(C_/32)*(HW_/32), 256, 0, stream>>>(cur, CT);
        cost_tr_kernel<<<(B_*HW_)/4, 256, 0, stream>>>(poses, Kmat, invKm,
                                                       LT, CT, cost, missing);
    } else {
        cost_naive_kernel<<<(B_*HW_ + 255)/256, 256, 0, stream>>>(
            cur, look, poses, Kmat, invKm, cost, missing);
    }
}